// Round 2
// baseline (971.062 us; speedup 1.0000x reference)
//
#include <hip/hip_runtime.h>

typedef __attribute__((ext_vector_type(8))) _Float16 half8;
typedef __attribute__((ext_vector_type(4))) _Float16 half4v;
typedef __attribute__((ext_vector_type(4))) float f32x4;
typedef __attribute__((ext_vector_type(4))) float float4v;

#define LDS_AS __attribute__((address_space(3)))
#define GL_AS __attribute__((address_space(1)))

static constexpr int Bn = 4, S = 2048, Dm = 1024, Hn = 16, DH = 64;
static constexpr int Mrows = Bn * S;   // 8192

// ---------------- fp32 -> fp16 convert ----------------
__global__ void cvt_f32_f16(const float* __restrict__ in, _Float16* __restrict__ out, int n4) {
  int idx = blockIdx.x * blockDim.x + threadIdx.x;
  int stride = gridDim.x * blockDim.x;
  for (int i = idx; i < n4; i += stride) {
    float4v v = ((const float4v*)in)[i];
    half4v h;
    h[0] = (_Float16)v[0]; h[1] = (_Float16)v[1];
    h[2] = (_Float16)v[2]; h[3] = (_Float16)v[3];
    ((half4v*)out)[i] = h;
  }
}

// ---------------- async global->LDS 16B (CK-style cast) ----------------
__device__ __forceinline__ void gload_lds16(const _Float16* g, _Float16* l) {
  auto* gp = reinterpret_cast<const GL_AS unsigned int*>(reinterpret_cast<uintptr_t>(g));
  auto* lp = reinterpret_cast<LDS_AS unsigned int*>(reinterpret_cast<uintptr_t>(l));
  __builtin_amdgcn_global_load_lds(gp, lp, 16, 0, 0);
}

// ---------------- 128x128 GEMM, C = A(MxK) * W(NxK)^T, fp16 MFMA ----------------
// WRITER 0: half out, [b][h][s][dh] (Q/K layout)
// WRITER 1: half out, [b][h][dh][s] (V^T layout)
// WRITER 2: float out, row-major MxN
template<int WRITER>
__global__ __launch_bounds__(256)
void gemm128(const _Float16* __restrict__ A, const _Float16* __restrict__ Bw,
             void* __restrict__ Cp) {
  constexpr int K = 1024, N = 1024;
  __shared__ __align__(16) _Float16 ldsA[128 * 32];
  __shared__ __align__(16) _Float16 ldsB[128 * 32];
  const int tid = threadIdx.x;
  const int lane = tid & 63, w = tid >> 6;
  const int r = lane & 15, g = lane >> 4;
  const int row0 = blockIdx.y * 128, col0 = blockIdx.x * 128;

  f32x4 acc[4][4] = {};

  // staging: chunk c (0..511), row=c>>2, slot=(c&3); logical colgrp = slot ^ (row&3)
  const int c0 = tid, c1 = 256 + tid;
  const int ar0 = c0 >> 2, as0 = (c0 & 3) ^ (ar0 & 3);
  const int ar1 = c1 >> 2, as1 = (c1 & 3) ^ (ar1 & 3);
  const _Float16* gA0 = A + (size_t)(row0 + ar0) * K + as0 * 8;
  const _Float16* gA1 = A + (size_t)(row0 + ar1) * K + as1 * 8;
  const _Float16* gB0 = Bw + (size_t)(col0 + ar0) * K + as0 * 8;
  const _Float16* gB1 = Bw + (size_t)(col0 + ar1) * K + as1 * 8;
  char* ldsA_b = (char*)ldsA;
  char* ldsB_b = (char*)ldsB;
  const int wm = (w >> 1) * 64, wn = (w & 1) * 64;
  const int swz = (r & 3) << 4;

  for (int kt = 0; kt < K / 32; ++kt) {
    gload_lds16(gA0 + kt * 32, (_Float16*)(ldsA_b + w * 1024));
    gload_lds16(gA1 + kt * 32, (_Float16*)(ldsA_b + 4096 + w * 1024));
    gload_lds16(gB0 + kt * 32, (_Float16*)(ldsB_b + w * 1024));
    gload_lds16(gB1 + kt * 32, (_Float16*)(ldsB_b + 4096 + w * 1024));
    __syncthreads();
    half8 af[4], bf[4];
#pragma unroll
    for (int i = 0; i < 4; ++i) {
      int rowA = wm + i * 16 + r;
      af[i] = *(const half8*)(ldsA_b + rowA * 64 + ((g * 16) ^ swz));
      int rowB = wn + i * 16 + r;
      bf[i] = *(const half8*)(ldsB_b + rowB * 64 + ((g * 16) ^ swz));
    }
#pragma unroll
    for (int i = 0; i < 4; ++i)
#pragma unroll
      for (int j = 0; j < 4; ++j)
        acc[i][j] = __builtin_amdgcn_mfma_f32_16x16x32_f16(af[i], bf[j], acc[i][j], 0, 0, 0);
    __syncthreads();
  }

#pragma unroll
  for (int i = 0; i < 4; ++i)
#pragma unroll
    for (int j = 0; j < 4; ++j)
#pragma unroll
      for (int jj = 0; jj < 4; ++jj) {
        int row = row0 + wm + i * 16 + g * 4 + jj;
        int col = col0 + wn + j * 16 + r;
        float v = acc[i][j][jj];
        if (WRITER == 2) {
          ((float*)Cp)[(size_t)row * N + col] = v;
        } else {
          int b = row >> 11, s = row & 2047;
          int h = col >> 6, dh = col & 63;
          _Float16 hv = (_Float16)v;
          if (WRITER == 0)
            ((_Float16*)Cp)[(((size_t)(b * Hn + h)) * S + s) * DH + dh] = hv;
          else
            ((_Float16*)Cp)[(((size_t)(b * Hn + h)) * DH + dh) * S + s] = hv;
        }
      }
}

// ---------------- flash attention with additive bias ----------------
// grid: (S/64, H, B), block 256 (4 waves x 16 q-rows)
__global__ __launch_bounds__(256)
void attn_kernel(const _Float16* __restrict__ Qg, const _Float16* __restrict__ Kg,
                 const _Float16* __restrict__ Vtg, const float* __restrict__ biasg,
                 _Float16* __restrict__ ctx) {
  __shared__ __align__(16) _Float16 Plds[4][16][72];
  const int tid = threadIdx.x;
  const int lane = tid & 63, w = tid >> 6;
  const int r = lane & 15, g = lane >> 4;
  const int h = blockIdx.y, b = blockIdx.z;
  const int q0 = blockIdx.x * 64 + w * 16;  // this wave's q rows
  const size_t head = ((size_t)(b * Hn + h)) * S * DH;
  const _Float16* Qh = Qg + head;
  const _Float16* Kh = Kg + head;
  const _Float16* Vh = Vtg + head;  // [DH][S]

  half8 aq[2];
  aq[0] = *(const half8*)(Qh + (size_t)(q0 + r) * DH + g * 8);
  aq[1] = *(const half8*)(Qh + (size_t)(q0 + r) * DH + 32 + g * 8);

  const float* biasp = biasg + (size_t)h * S * S + (size_t)(q0 + g * 4) * S + r;

  f32x4 acc_o[4] = {};
  float m_run[4] = {-INFINITY, -INFINITY, -INFINITY, -INFINITY};
  float l_run[4] = {0.f, 0.f, 0.f, 0.f};
  _Float16* pbase = &Plds[w][0][0];

  for (int kt = 0; kt < S / 64; ++kt) {
    const int k0 = kt * 64;
    // QK^T: S-tile 16q x 64k in 4 frags
    f32x4 sf[4];
#pragma unroll
    for (int f = 0; f < 4; ++f) {
      half8 b0 = *(const half8*)(Kh + (size_t)(k0 + f * 16 + r) * DH + g * 8);
      half8 b1 = *(const half8*)(Kh + (size_t)(k0 + f * 16 + r) * DH + 32 + g * 8);
      f32x4 a = {};
      a = __builtin_amdgcn_mfma_f32_16x16x32_f16(aq[0], b0, a, 0, 0, 0);
      a = __builtin_amdgcn_mfma_f32_16x16x32_f16(aq[1], b1, a, 0, 0, 0);
      sf[f] = a;
    }
    // + bias (fp32)
    float p[4][4];
#pragma unroll
    for (int f = 0; f < 4; ++f)
#pragma unroll
      for (int jj = 0; jj < 4; ++jj)
        p[f][jj] = sf[f][jj] + biasp[(size_t)jj * S + k0 + f * 16];
    // online softmax per q-row (row = g*4+jj, 16 lanes share a row)
#pragma unroll
    for (int jj = 0; jj < 4; ++jj) {
      float tmax = fmaxf(fmaxf(p[0][jj], p[1][jj]), fmaxf(p[2][jj], p[3][jj]));
#pragma unroll
      for (int off = 1; off < 16; off <<= 1) tmax = fmaxf(tmax, __shfl_xor(tmax, off));
      float mnew = fmaxf(m_run[jj], tmax);
      float scale = __expf(m_run[jj] - mnew);
      float ps = 0.f;
#pragma unroll
      for (int f = 0; f < 4; ++f) {
        p[f][jj] = __expf(p[f][jj] - mnew);
        ps += p[f][jj];
      }
#pragma unroll
      for (int off = 1; off < 16; off <<= 1) ps += __shfl_xor(ps, off);
      l_run[jj] = l_run[jj] * scale + ps;
      m_run[jj] = mnew;
#pragma unroll
      for (int gi = 0; gi < 4; ++gi) acc_o[gi][jj] *= scale;
    }
    // P -> LDS (transpose to A-fragment layout), per-wave region
#pragma unroll
    for (int f = 0; f < 4; ++f)
#pragma unroll
      for (int jj = 0; jj < 4; ++jj)
        pbase[(g * 4 + jj) * 72 + f * 16 + r] = (_Float16)p[f][jj];
    asm volatile("s_waitcnt lgkmcnt(0)" ::: "memory");
    // PV: ctx(16x64) += P(16x64) * V(64x64)
#pragma unroll
    for (int ks = 0; ks < 2; ++ks) {
      half8 pa = *(const half8*)((const char*)pbase + r * 144 + (ks * 32 + g * 8) * 2);
#pragma unroll
      for (int gi = 0; gi < 4; ++gi) {
        half8 bv = *(const half8*)(Vh + (size_t)(gi * 16 + r) * S + k0 + ks * 32 + g * 8);
        acc_o[gi] = __builtin_amdgcn_mfma_f32_16x16x32_f16(pa, bv, acc_o[gi], 0, 0, 0);
      }
    }
  }
  // epilogue: normalize, write ctx [b][s][h*64+dh] as fp16
#pragma unroll
  for (int jj = 0; jj < 4; ++jj) {
    float inv = 1.f / l_run[jj];
    int qrow = q0 + g * 4 + jj;
#pragma unroll
    for (int gi = 0; gi < 4; ++gi)
      ctx[((size_t)(b * S + qrow)) * Dm + h * DH + gi * 16 + r] =
          (_Float16)(acc_o[gi][jj] * inv);
  }
}

// ---------------- launch ----------------
extern "C" void kernel_launch(void* const* d_in, const int* in_sizes, int n_in,
                              void* d_out, int out_size, void* d_ws, size_t ws_size,
                              hipStream_t stream) {
  const float* X = (const float*)d_in[0];
  const float* bias = (const float*)d_in[1];
  const float* Wq = (const float*)d_in[2];
  const float* Wk = (const float*)d_in[3];
  const float* Wv = (const float*)d_in[4];
  const float* Wo = (const float*)d_in[5];
  float* out = (float*)d_out;

  char* ws = (char*)d_ws;
  _Float16* Xh = (_Float16*)ws;                       // 8192x1024 (also reused as ctx)
  _Float16* Wqh = (_Float16*)(ws + 16777216);
  _Float16* Wkh = Wqh + 1048576;
  _Float16* Wvh = Wkh + 1048576;
  _Float16* Woh = Wvh + 1048576;
  _Float16* Qb = (_Float16*)(ws + 16777216 + 8388608);
  _Float16* Kb = Qb + 8388608;
  _Float16* Vtb = Kb + 8388608;

  cvt_f32_f16<<<2048, 256, 0, stream>>>(X, Xh, (Mrows * Dm) / 4);
  cvt_f32_f16<<<512, 256, 0, stream>>>(Wq, Wqh, (Dm * Dm) / 4);
  cvt_f32_f16<<<512, 256, 0, stream>>>(Wk, Wkh, (Dm * Dm) / 4);
  cvt_f32_f16<<<512, 256, 0, stream>>>(Wv, Wvh, (Dm * Dm) / 4);
  cvt_f32_f16<<<512, 256, 0, stream>>>(Wo, Woh, (Dm * Dm) / 4);

  dim3 gg(Dm / 128, Mrows / 128);  // (8, 64)
  gemm128<0><<<gg, 256, 0, stream>>>(Xh, Wqh, (void*)Qb);
  gemm128<0><<<gg, 256, 0, stream>>>(Xh, Wkh, (void*)Kb);
  gemm128<1><<<gg, 256, 0, stream>>>(Xh, Wvh, (void*)Vtb);

  dim3 ga(S / 64, Hn, Bn);  // (32, 16, 4)
  attn_kernel<<<ga, 256, 0, stream>>>(Qb, Kb, Vtb, bias, Xh);  // ctx overwrites Xh

  gemm128<2><<<gg, 256, 0, stream>>>(Xh, Woh, (void*)out);
}

// Round 3
// 920.898 us; speedup vs baseline: 1.0545x; 1.0545x over previous
//
#include <hip/hip_runtime.h>

typedef __attribute__((ext_vector_type(8))) _Float16 half8;
typedef __attribute__((ext_vector_type(4))) _Float16 half4v;
typedef __attribute__((ext_vector_type(4))) float f32x4;
typedef __attribute__((ext_vector_type(4))) float float4v;

#define LDS_AS __attribute__((address_space(3)))
#define GL_AS __attribute__((address_space(1)))

static constexpr int Bn = 4, S = 2048, Dm = 1024, Hn = 16, DH = 64;
static constexpr int Mrows = Bn * S;   // 8192

// ---------------- fp32 -> fp16 convert ----------------
__global__ void cvt_f32_f16(const float* __restrict__ in, _Float16* __restrict__ out, int n4) {
  int idx = blockIdx.x * blockDim.x + threadIdx.x;
  int stride = gridDim.x * blockDim.x;
  for (int i = idx; i < n4; i += stride) {
    float4v v = ((const float4v*)in)[i];
    half4v h;
    h[0] = (_Float16)v[0]; h[1] = (_Float16)v[1];
    h[2] = (_Float16)v[2]; h[3] = (_Float16)v[3];
    ((half4v*)out)[i] = h;
  }
}

// ---------------- async global->LDS 16B (CK-style cast) ----------------
__device__ __forceinline__ void gload_lds16(const void* g, void* l) {
  auto* gp = reinterpret_cast<const GL_AS unsigned int*>(reinterpret_cast<uintptr_t>(g));
  auto* lp = reinterpret_cast<LDS_AS unsigned int*>(reinterpret_cast<uintptr_t>(l));
  __builtin_amdgcn_global_load_lds(gp, lp, 16, 0, 0);
}

// ---------------- 128x128 GEMM, C = A(MxK) * W(NxK)^T, fp16 MFMA ----------------
// WRITER 0: half out, [b][h][s][dh] (Q/K layout)
// WRITER 1: half out, [b][h][dh][s] (V^T layout)
// WRITER 2: float out, row-major MxN
template<int WRITER>
__global__ __launch_bounds__(256)
void gemm128(const _Float16* __restrict__ A, const _Float16* __restrict__ Bw,
             void* __restrict__ Cp) {
  constexpr int K = 1024, N = 1024;
  __shared__ __align__(16) _Float16 ldsA[128 * 32];
  __shared__ __align__(16) _Float16 ldsB[128 * 32];
  const int tid = threadIdx.x;
  const int lane = tid & 63, w = tid >> 6;
  const int r = lane & 15, g = lane >> 4;
  const int row0 = blockIdx.y * 128, col0 = blockIdx.x * 128;

  f32x4 acc[4][4] = {};

  // staging: chunk c (0..511), row=c>>2, slot=(c&3); logical colgrp = slot ^ (row&3)
  const int c0 = tid, c1 = 256 + tid;
  const int ar0 = c0 >> 2, as0 = (c0 & 3) ^ (ar0 & 3);
  const int ar1 = c1 >> 2, as1 = (c1 & 3) ^ (ar1 & 3);
  const _Float16* gA0 = A + (size_t)(row0 + ar0) * K + as0 * 8;
  const _Float16* gA1 = A + (size_t)(row0 + ar1) * K + as1 * 8;
  const _Float16* gB0 = Bw + (size_t)(col0 + ar0) * K + as0 * 8;
  const _Float16* gB1 = Bw + (size_t)(col0 + ar1) * K + as1 * 8;
  char* ldsA_b = (char*)ldsA;
  char* ldsB_b = (char*)ldsB;
  const int wm = (w >> 1) * 64, wn = (w & 1) * 64;
  const int swz = (r & 3) << 4;

  for (int kt = 0; kt < K / 32; ++kt) {
    gload_lds16(gA0 + kt * 32, (_Float16*)(ldsA_b + w * 1024));
    gload_lds16(gA1 + kt * 32, (_Float16*)(ldsA_b + 4096 + w * 1024));
    gload_lds16(gB0 + kt * 32, (_Float16*)(ldsB_b + w * 1024));
    gload_lds16(gB1 + kt * 32, (_Float16*)(ldsB_b + 4096 + w * 1024));
    __syncthreads();
    half8 af[4], bf[4];
#pragma unroll
    for (int i = 0; i < 4; ++i) {
      int rowA = wm + i * 16 + r;
      af[i] = *(const half8*)(ldsA_b + rowA * 64 + ((g * 16) ^ swz));
      int rowB = wn + i * 16 + r;
      bf[i] = *(const half8*)(ldsB_b + rowB * 64 + ((g * 16) ^ swz));
    }
#pragma unroll
    for (int i = 0; i < 4; ++i)
#pragma unroll
      for (int j = 0; j < 4; ++j)
        acc[i][j] = __builtin_amdgcn_mfma_f32_16x16x32_f16(af[i], bf[j], acc[i][j], 0, 0, 0);
    __syncthreads();
  }

#pragma unroll
  for (int i = 0; i < 4; ++i)
#pragma unroll
    for (int j = 0; j < 4; ++j)
#pragma unroll
      for (int jj = 0; jj < 4; ++jj) {
        int row = row0 + wm + i * 16 + g * 4 + jj;
        int col = col0 + wn + j * 16 + r;
        float v = acc[i][j][jj];
        if (WRITER == 2) {
          ((float*)Cp)[(size_t)row * N + col] = v;
        } else {
          int b = row >> 11, s = row & 2047;
          int h = col >> 6, dh = col & 63;
          _Float16 hv = (_Float16)v;
          if (WRITER == 0)
            ((_Float16*)Cp)[(((size_t)(b * Hn + h)) * S + s) * DH + dh] = hv;
          else
            ((_Float16*)Cp)[(((size_t)(b * Hn + h)) * DH + dh) * S + s] = hv;
        }
      }
}

// ---------------- flash attention with additive bias ----------------
// grid: (S/64, H), block 1024 (16 waves). Wave w: batch = w>>2, qsub = w&3.
// Bias tile (64 q-rows x 64 k-cols, fp32) staged in LDS per kt, double-buffered,
// shared across the 4 batches -> 4x bias HBM traffic cut + async load.
__global__ __launch_bounds__(1024)
void attn_kernel(const _Float16* __restrict__ Qg, const _Float16* __restrict__ Kg,
                 const _Float16* __restrict__ Vtg, const float* __restrict__ biasg,
                 _Float16* __restrict__ ctx) {
  __shared__ __align__(16) float bias_lds[2][64 * 64];
  __shared__ __align__(16) _Float16 Plds[16][16 * 72];
  const int tid = threadIdx.x;
  const int lane = tid & 63, w = tid >> 6;
  const int r = lane & 15, g = lane >> 4;
  const int h = blockIdx.y;
  const int bq = w >> 2, qsub = w & 3;
  const int q0b = blockIdx.x * 64;
  const int q0 = q0b + qsub * 16;  // this wave's q rows
  const size_t head = ((size_t)(bq * Hn + h)) * S * DH;
  const _Float16* Qh = Qg + head;
  const _Float16* Kh = Kg + head;
  const _Float16* Vh = Vtg + head;  // [DH][S]

  half8 aq[2];
  aq[0] = *(const half8*)(Qh + (size_t)(q0 + r) * DH + g * 8);
  aq[1] = *(const half8*)(Qh + (size_t)(q0 + r) * DH + 32 + g * 8);

  // bias staging: thread t loads 16B for tile row t>>4, chunk t&15 (linear in t)
  const float* bsrc = biasg + (size_t)h * S * S + (size_t)(q0b + (tid >> 4)) * S + (tid & 15) * 4;
  float* bdst0 = &bias_lds[0][0] + tid * 4;
  float* bdst1 = &bias_lds[1][0] + tid * 4;

  f32x4 acc_o[4] = {};
  float m_run[4] = {-INFINITY, -INFINITY, -INFINITY, -INFINITY};
  float l_run[4] = {0.f, 0.f, 0.f, 0.f};
  _Float16* pbase = &Plds[w][0];
  const int rowl = qsub * 16 + g * 4;  // + jj -> local q row within 64-row tile

  gload_lds16(bsrc, bdst0);
  __syncthreads();  // staging of buf0 complete (vmcnt drained by barrier)

  for (int kt = 0; kt < S / 64; ++kt) {
    const int k0 = kt * 64;
    // prefetch next bias tile into the other buffer (all waves past prior barrier)
    if (kt + 1 < S / 64) gload_lds16(bsrc + (kt + 1) * 64, (kt & 1) ? bdst0 : bdst1);
    const float* bb = (kt & 1) ? &bias_lds[1][0] : &bias_lds[0][0];

    // QK^T: S-tile 16q x 64k in 4 frags
    f32x4 sf[4];
#pragma unroll
    for (int f = 0; f < 4; ++f) {
      half8 b0 = *(const half8*)(Kh + (size_t)(k0 + f * 16 + r) * DH + g * 8);
      half8 b1 = *(const half8*)(Kh + (size_t)(k0 + f * 16 + r) * DH + 32 + g * 8);
      f32x4 a = {};
      a = __builtin_amdgcn_mfma_f32_16x16x32_f16(aq[0], b0, a, 0, 0, 0);
      a = __builtin_amdgcn_mfma_f32_16x16x32_f16(aq[1], b1, a, 0, 0, 0);
      sf[f] = a;
    }
    // + bias (fp32, from LDS)
    float p[4][4];
#pragma unroll
    for (int f = 0; f < 4; ++f)
#pragma unroll
      for (int jj = 0; jj < 4; ++jj)
        p[f][jj] = sf[f][jj] + bb[(rowl + jj) * 64 + f * 16 + r];
    // online softmax per q-row (row = g*4+jj, 16 lanes share a row)
#pragma unroll
    for (int jj = 0; jj < 4; ++jj) {
      float tmax = fmaxf(fmaxf(p[0][jj], p[1][jj]), fmaxf(p[2][jj], p[3][jj]));
#pragma unroll
      for (int off = 1; off < 16; off <<= 1) tmax = fmaxf(tmax, __shfl_xor(tmax, off));
      float mnew = fmaxf(m_run[jj], tmax);
      float scale = __expf(m_run[jj] - mnew);
      float ps = 0.f;
#pragma unroll
      for (int f = 0; f < 4; ++f) {
        p[f][jj] = __expf(p[f][jj] - mnew);
        ps += p[f][jj];
      }
#pragma unroll
      for (int off = 1; off < 16; off <<= 1) ps += __shfl_xor(ps, off);
      l_run[jj] = l_run[jj] * scale + ps;
      m_run[jj] = mnew;
#pragma unroll
      for (int gi = 0; gi < 4; ++gi) acc_o[gi][jj] *= scale;
    }
    // P -> LDS (transpose to A-fragment layout), per-wave region
#pragma unroll
    for (int f = 0; f < 4; ++f)
#pragma unroll
      for (int jj = 0; jj < 4; ++jj)
        pbase[(rowl - qsub * 16 + jj) * 72 + f * 16 + r] = (_Float16)p[f][jj];
    asm volatile("s_waitcnt lgkmcnt(0)" ::: "memory");
    // PV: ctx(16x64) += P(16x64) * V(64x64)
#pragma unroll
    for (int ks = 0; ks < 2; ++ks) {
      half8 pa = *(const half8*)((const char*)pbase + r * 144 + (ks * 32 + g * 8) * 2);
#pragma unroll
      for (int gi = 0; gi < 4; ++gi) {
        half8 bv = *(const half8*)(Vh + (size_t)(gi * 16 + r) * S + k0 + ks * 32 + g * 8);
        acc_o[gi] = __builtin_amdgcn_mfma_f32_16x16x32_f16(pa, bv, acc_o[gi], 0, 0, 0);
      }
    }
    __syncthreads();  // staging of next tile done; all waves done reading bb
  }
  // epilogue: normalize, write ctx [b][s][h*64+dh] as fp16
#pragma unroll
  for (int jj = 0; jj < 4; ++jj) {
    float inv = 1.f / l_run[jj];
    int qrow = q0 + g * 4 + jj;
#pragma unroll
    for (int gi = 0; gi < 4; ++gi)
      ctx[((size_t)(bq * S + qrow)) * Dm + h * DH + gi * 16 + r] =
          (_Float16)(acc_o[gi][jj] * inv);
  }
}

// ---------------- launch ----------------
extern "C" void kernel_launch(void* const* d_in, const int* in_sizes, int n_in,
                              void* d_out, int out_size, void* d_ws, size_t ws_size,
                              hipStream_t stream) {
  const float* X = (const float*)d_in[0];
  const float* bias = (const float*)d_in[1];
  const float* Wq = (const float*)d_in[2];
  const float* Wk = (const float*)d_in[3];
  const float* Wv = (const float*)d_in[4];
  const float* Wo = (const float*)d_in[5];
  float* out = (float*)d_out;

  char* ws = (char*)d_ws;
  _Float16* Xh = (_Float16*)ws;                       // 8192x1024 (also reused as ctx)
  _Float16* Wqh = (_Float16*)(ws + 16777216);
  _Float16* Wkh = Wqh + 1048576;
  _Float16* Wvh = Wkh + 1048576;
  _Float16* Woh = Wvh + 1048576;
  _Float16* Qb = (_Float16*)(ws + 16777216 + 8388608);
  _Float16* Kb = Qb + 8388608;
  _Float16* Vtb = Kb + 8388608;

  cvt_f32_f16<<<2048, 256, 0, stream>>>(X, Xh, (Mrows * Dm) / 4);
  cvt_f32_f16<<<512, 256, 0, stream>>>(Wq, Wqh, (Dm * Dm) / 4);
  cvt_f32_f16<<<512, 256, 0, stream>>>(Wk, Wkh, (Dm * Dm) / 4);
  cvt_f32_f16<<<512, 256, 0, stream>>>(Wv, Wvh, (Dm * Dm) / 4);
  cvt_f32_f16<<<512, 256, 0, stream>>>(Wo, Woh, (Dm * Dm) / 4);

  dim3 gg(Dm / 128, Mrows / 128);  // (8, 64)
  gemm128<0><<<gg, 256, 0, stream>>>(Xh, Wqh, (void*)Qb);
  gemm128<0><<<gg, 256, 0, stream>>>(Xh, Wkh, (void*)Kb);
  gemm128<1><<<gg, 256, 0, stream>>>(Xh, Wvh, (void*)Vtb);

  dim3 ga(S / 64, Hn);  // (32, 16); block covers all 4 batches
  attn_kernel<<<ga, 1024, 0, stream>>>(Qb, Kb, Vtb, bias, Xh);  // ctx overwrites Xh

  gemm128<2><<<gg, 256, 0, stream>>>(Xh, Woh, (void*)out);
}